// Round 3
// baseline (547.700 us; speedup 1.0000x reference)
//
#include <hip/hip_runtime.h>
#include <math.h>

#define N_NODES 50000
#define N_EDGES 800000
#define D 64
#define NB_SCAN ((N_NODES + 255) / 256)   // 196 blocks of 256

typedef float f32x4 __attribute__((ext_vector_type(4)));   // native vector for nontemporal builtins

// ---------------------------------------------------------------------------
// Phase 1: histogram of src -> cnt[n]  (int atomics, 800K ops)
// ---------------------------------------------------------------------------
__global__ __launch_bounds__(256) void hist_kernel(
    const int* __restrict__ edge_index, int* __restrict__ cnt)
{
    int e = blockIdx.x * blockDim.x + threadIdx.x;
    if (e >= N_EDGES) return;
    atomicAdd(&cnt[edge_index[e]], 1);
}

// ---------------------------------------------------------------------------
// Phase 2: exclusive scan of cnt -> offs  (3 tiny kernels)
// ---------------------------------------------------------------------------
__global__ __launch_bounds__(256) void scanA_kernel(
    const int* __restrict__ cnt, int* __restrict__ offs, int* __restrict__ bsum)
{
    __shared__ int tmp[256];
    int tid = threadIdx.x;
    int i = blockIdx.x * 256 + tid;
    int v = (i < N_NODES) ? cnt[i] : 0;
    tmp[tid] = v;
    __syncthreads();
    for (int s = 1; s < 256; s <<= 1) {
        int add = (tid >= s) ? tmp[tid - s] : 0;
        __syncthreads();
        tmp[tid] += add;
        __syncthreads();
    }
    if (i < N_NODES) offs[i] = tmp[tid] - v;          // exclusive
    if (tid == 255) bsum[blockIdx.x] = tmp[255];      // block total
}

__global__ __launch_bounds__(256) void scanB_kernel(int* __restrict__ bsum)
{
    __shared__ int tmp[256];
    int tid = threadIdx.x;
    int v = (tid < NB_SCAN) ? bsum[tid] : 0;
    tmp[tid] = v;
    __syncthreads();
    for (int s = 1; s < 256; s <<= 1) {
        int add = (tid >= s) ? tmp[tid - s] : 0;
        __syncthreads();
        tmp[tid] += add;
        __syncthreads();
    }
    bsum[tid] = tmp[tid] - v;                          // exclusive block offsets
}

__global__ __launch_bounds__(256) void scanC_kernel(
    int* __restrict__ offs, const int* __restrict__ bsum, int* __restrict__ cursor)
{
    int i = blockIdx.x * 256 + threadIdx.x;
    if (i >= N_NODES) return;
    int o = offs[i] + bsum[blockIdx.x];
    offs[i] = o;
    cursor[i] = o;
}

// ---------------------------------------------------------------------------
// Phase 3: bucket edge ids by src (counting-sort fill)
// ---------------------------------------------------------------------------
__global__ __launch_bounds__(256) void fill_kernel(
    const int* __restrict__ edge_index, int* __restrict__ cursor,
    int* __restrict__ bucket)
{
    int e = blockIdx.x * blockDim.x + threadIdx.x;
    if (e >= N_EDGES) return;
    int src = edge_index[e];
    int pos = atomicAdd(&cursor[src], 1);
    bucket[pos] = e;
}

// ---------------------------------------------------------------------------
// Phase 4 (fused): per-node gather-mean + linear + sigmoid.
// One wave per node. Lane decomposition THIS ROUND:
//   sub = lane>>4  : which edge within a group of 4
//   q   = lane&15  : feature quad (features 4q..4q+3), f32x4 per lane
// One wave step consumes 4 edges (4 x 256 B contiguous). 4-deep unroll ->
// 16 edges / 4 KB in flight per wave. Cross-sub reduce = 2x shfl_xor.
// GEMM: ms[i] broadcast via __shfl(ms[i&3], i>>2) -- component index is
// compile-time under #pragma unroll, no LDS buffer needed.
// edge_attr/node_attr are read exactly once -> nontemporal loads.
// ---------------------------------------------------------------------------
__global__ __launch_bounds__(256) void node_fused_kernel(
    const float* __restrict__ node_attr,
    const float* __restrict__ edge_attr,
    const int* __restrict__ cnt,
    const int* __restrict__ offs,
    const int* __restrict__ bucket,
    const float* __restrict__ W,
    const float* __restrict__ bias,
    float* __restrict__ node_emb)
{
    __shared__ float Wt[D * (D + 1)];     // stride-65 padded: 2-way banks everywhere
    int tid = threadIdx.x;
    for (int k = tid; k < D * D; k += 256) {
        int o = k >> 6, i = k & 63;
        Wt[i * (D + 1) + o] = W[k];
    }
    __syncthreads();

    int n = blockIdx.x * 4 + (tid >> 6);
    int lane = tid & 63;
    if (n >= N_NODES) return;

    int c   = cnt[n];
    int beg = offs[n];
    const int* __restrict__ bk = bucket + beg;

    int sub = lane >> 4;          // 0..3
    int q   = lane & 15;          // feature quad

    f32x4 s0 = {0.f,0.f,0.f,0.f}, s1 = s0, s2 = s0, s3 = s0;
    int k = 0;
    for (; k + 16 <= c; k += 16) {
        int ea = bk[k +  0 + sub];
        int eb = bk[k +  4 + sub];
        int ec = bk[k +  8 + sub];
        int ed = bk[k + 12 + sub];
        s0 += __builtin_nontemporal_load((const f32x4*)(edge_attr + (size_t)ea * D) + q);
        s1 += __builtin_nontemporal_load((const f32x4*)(edge_attr + (size_t)eb * D) + q);
        s2 += __builtin_nontemporal_load((const f32x4*)(edge_attr + (size_t)ec * D) + q);
        s3 += __builtin_nontemporal_load((const f32x4*)(edge_attr + (size_t)ed * D) + q);
    }
    for (; k + 4 <= c; k += 4) {
        int ea = bk[k + sub];
        s0 += __builtin_nontemporal_load((const f32x4*)(edge_attr + (size_t)ea * D) + q);
    }
    int rem = c - k;              // 0..3 leftover edges
    if (sub < rem) {
        int ea = bk[k + sub];
        s1 += __builtin_nontemporal_load((const f32x4*)(edge_attr + (size_t)ea * D) + q);
    }
    f32x4 s = (s0 + s1) + (s2 + s3);

    // reduce across the 4 sub-groups: lanes l, l^16, l^32, l^48
    s.x += __shfl_xor(s.x, 16, 64); s.y += __shfl_xor(s.y, 16, 64);
    s.z += __shfl_xor(s.z, 16, 64); s.w += __shfl_xor(s.w, 16, 64);
    s.x += __shfl_xor(s.x, 32, 64); s.y += __shfl_xor(s.y, 32, 64);
    s.z += __shfl_xor(s.z, 32, 64); s.w += __shfl_xor(s.w, 32, 64);

    float scale = 0.5f / (float)((c > 0) ? c : 1);
    f32x4 na = __builtin_nontemporal_load((const f32x4*)(node_attr + (size_t)n * D) + q);
    f32x4 ms = na + s * scale;    // every lane holds features 4q..4q+3

    float acc = bias[lane];
    #pragma unroll
    for (int i = 0; i < D; ++i) {
        // feature i lives in lanes with (lane&15)==i>>2, component i&3 (compile-time)
        float m = __shfl(ms[i & 3], i >> 2, 64);
        acc = fmaf(m, Wt[i * (D + 1) + lane], acc);
    }
    node_emb[(size_t)n * D + lane] = 1.0f / (1.0f + __expf(-acc));
}

// ---------------------------------------------------------------------------
// Phase 5: out[e] = 0.5*(node_emb[src[e]] + node_emb[dst[e]])
// 32 B per thread (2 x f32x4): half the threads / index loads of last round.
// Output written once, never re-read -> non-temporal stores.
// ---------------------------------------------------------------------------
__global__ __launch_bounds__(256) void edge_kernel(
    const int* __restrict__ edge_index,
    const f32x4* __restrict__ node_emb,   // [N_NODES*16] vec4
    f32x4* __restrict__ out)              // [N_EDGES*16] vec4
{
    int t = blockIdx.x * blockDim.x + threadIdx.x;   // < E*8 = 6.4M
    if (t >= N_EDGES * 8) return;
    int e = t >> 3;
    int q = t & 7;                 // 32-B chunk
    int src = edge_index[e];
    int dst = edge_index[N_EDGES + e];
    f32x4 a0 = node_emb[src * 16 + 2 * q];
    f32x4 a1 = node_emb[src * 16 + 2 * q + 1];
    f32x4 c0 = node_emb[dst * 16 + 2 * q];
    f32x4 c1 = node_emb[dst * 16 + 2 * q + 1];
    __builtin_nontemporal_store((a0 + c0) * 0.5f, out + 2 * t);
    __builtin_nontemporal_store((a1 + c1) * 0.5f, out + 2 * t + 1);
}

extern "C" void kernel_launch(void* const* d_in, const int* in_sizes, int n_in,
                              void* d_out, int out_size, void* d_ws, size_t ws_size,
                              hipStream_t stream) {
    const float* edge_attr  = (const float*)d_in[0];
    const int*   edge_index = (const int*)d_in[1];
    const float* node_attr  = (const float*)d_in[2];
    const float* W          = (const float*)d_in[3];
    const float* bias       = (const float*)d_in[4];
    float* out = (float*)d_out;

    // Workspace layout:
    //   cnt    : int[N_NODES]      @ 0
    //   offs   : int[N_NODES]      @ 200000 B
    //   bsum   : int[256]          @ 400000 B
    //   cursor : int[N_NODES]      @ 401024 B
    //   bucket : int[N_EDGES]      @ 601024 B
    //   node_emb: float[N_NODES*D] @ 3801024 B (16B-aligned)
    char* ws = (char*)d_ws;
    int*   cnt      = (int*)(ws);
    int*   offs     = (int*)(ws + 200000);
    int*   bsum     = (int*)(ws + 400000);
    int*   cursor   = (int*)(ws + 401024);
    int*   bucket   = (int*)(ws + 601024);
    float* node_emb = (float*)(ws + 3801024);

    hipMemsetAsync(cnt, 0, N_NODES * sizeof(int), stream);

    hist_kernel<<<(N_EDGES + 255) / 256, 256, 0, stream>>>(edge_index, cnt);
    scanA_kernel<<<NB_SCAN, 256, 0, stream>>>(cnt, offs, bsum);
    scanB_kernel<<<1, 256, 0, stream>>>(bsum);
    scanC_kernel<<<NB_SCAN, 256, 0, stream>>>(offs, bsum, cursor);
    fill_kernel<<<(N_EDGES + 255) / 256, 256, 0, stream>>>(edge_index, cursor, bucket);
    node_fused_kernel<<<(N_NODES + 3) / 4, 256, 0, stream>>>(
        node_attr, edge_attr, cnt, offs, bucket, W, bias, node_emb);
    edge_kernel<<<(N_EDGES * 8 + 255) / 256, 256, 0, stream>>>(
        edge_index, (const f32x4*)node_emb, (f32x4*)out);
}

// Round 4
// 537.106 us; speedup vs baseline: 1.0197x; 1.0197x over previous
//
#include <hip/hip_runtime.h>
#include <math.h>

#define N_NODES 50000
#define N_EDGES 800000
#define D 64
#define NB_SCAN ((N_NODES + 255) / 256)   // 196 blocks of 256

typedef float f32x4 __attribute__((ext_vector_type(4)));   // native vector for nontemporal builtins

// ---------------------------------------------------------------------------
// Phase 1: histogram of src -> cnt[n]  (int atomics, 800K ops)
// ---------------------------------------------------------------------------
__global__ __launch_bounds__(256) void hist_kernel(
    const int* __restrict__ edge_index, int* __restrict__ cnt)
{
    int e = blockIdx.x * blockDim.x + threadIdx.x;
    if (e >= N_EDGES) return;
    atomicAdd(&cnt[edge_index[e]], 1);
}

// ---------------------------------------------------------------------------
// Phase 2: exclusive scan of cnt -> offs  (3 tiny kernels)
// ---------------------------------------------------------------------------
__global__ __launch_bounds__(256) void scanA_kernel(
    const int* __restrict__ cnt, int* __restrict__ offs, int* __restrict__ bsum)
{
    __shared__ int tmp[256];
    int tid = threadIdx.x;
    int i = blockIdx.x * 256 + tid;
    int v = (i < N_NODES) ? cnt[i] : 0;
    tmp[tid] = v;
    __syncthreads();
    for (int s = 1; s < 256; s <<= 1) {
        int add = (tid >= s) ? tmp[tid - s] : 0;
        __syncthreads();
        tmp[tid] += add;
        __syncthreads();
    }
    if (i < N_NODES) offs[i] = tmp[tid] - v;          // exclusive
    if (tid == 255) bsum[blockIdx.x] = tmp[255];      // block total
}

__global__ __launch_bounds__(256) void scanB_kernel(int* __restrict__ bsum)
{
    __shared__ int tmp[256];
    int tid = threadIdx.x;
    int v = (tid < NB_SCAN) ? bsum[tid] : 0;
    tmp[tid] = v;
    __syncthreads();
    for (int s = 1; s < 256; s <<= 1) {
        int add = (tid >= s) ? tmp[tid - s] : 0;
        __syncthreads();
        tmp[tid] += add;
        __syncthreads();
    }
    bsum[tid] = tmp[tid] - v;                          // exclusive block offsets
}

__global__ __launch_bounds__(256) void scanC_kernel(
    int* __restrict__ offs, const int* __restrict__ bsum, int* __restrict__ cursor)
{
    int i = blockIdx.x * 256 + threadIdx.x;
    if (i >= N_NODES) return;
    int o = offs[i] + bsum[blockIdx.x];
    offs[i] = o;
    cursor[i] = o;
}

// ---------------------------------------------------------------------------
// Phase 3: bucket edge ids by src (counting-sort fill)
// ---------------------------------------------------------------------------
__global__ __launch_bounds__(256) void fill_kernel(
    const int* __restrict__ edge_index, int* __restrict__ cursor,
    int* __restrict__ bucket)
{
    int e = blockIdx.x * blockDim.x + threadIdx.x;
    if (e >= N_EDGES) return;
    int src = edge_index[e];
    int pos = atomicAdd(&cursor[src], 1);
    bucket[pos] = e;
}

// ---------------------------------------------------------------------------
// Phase 4 (fused): per-node gather-mean + linear + sigmoid.
// One wave per node. Lane decomposition:
//   sub = lane>>4 : which edge within a group of 4
//   q   = lane&15 : feature quad (features 4q..4q+3), f32x4 per lane
// Changes this round:
//   * REVERTED nontemporal on gather loads: round-0 counters showed L3 was
//     absorbing ~95 MB of edge_attr re-fetch (FETCH 110 MB vs 205 MB logical);
//     NT hints bypassed that and cost ~+15 us in round 3.
//   * MLP broadcast restructured: was 64 ds_bpermute (shfl) + 64 ds_read_b32
//     per wave (128 LDS-pipe ops, the real critical path). Now: sub==0 lanes
//     write the ms row to a per-wave LDS buffer (1 conflict-free b128 write),
//     GEMM reads it back as 16 wave-uniform ds_read_b128 broadcasts + the
//     64 conflict-free Wt b32 reads. Same-wave write->read fenced with
//     s_waitcnt lgkmcnt(0) + sched_barrier(0) (no block barrier).
// ---------------------------------------------------------------------------
__global__ __launch_bounds__(256) void node_fused_kernel(
    const float* __restrict__ node_attr,
    const float* __restrict__ edge_attr,
    const int* __restrict__ cnt,
    const int* __restrict__ offs,
    const int* __restrict__ bucket,
    const float* __restrict__ W,
    const float* __restrict__ bias,
    float* __restrict__ node_emb)
{
    __shared__ float Wt[D * (D + 1)];     // Wt[i*65+o] = W[o][i]; 2-way banks everywhere
    __shared__ f32x4 msbuf[4][16];        // per-wave ms row (64 floats as 16 quads)
    int tid = threadIdx.x;
    for (int k = tid; k < D * D; k += 256) {
        int o = k >> 6, i = k & 63;
        Wt[i * (D + 1) + o] = W[k];
    }
    __syncthreads();

    int wv   = tid >> 6;
    int n    = blockIdx.x * 4 + wv;
    int lane = tid & 63;
    if (n >= N_NODES) return;

    int c   = cnt[n];
    int beg = offs[n];
    const int* __restrict__ bk = bucket + beg;

    int sub = lane >> 4;          // 0..3
    int q   = lane & 15;          // feature quad

    f32x4 s0 = {0.f,0.f,0.f,0.f}, s1 = s0, s2 = s0, s3 = s0;
    int k = 0;
    for (; k + 16 <= c; k += 16) {
        int ea = bk[k +  0 + sub];
        int eb = bk[k +  4 + sub];
        int ec = bk[k +  8 + sub];
        int ed = bk[k + 12 + sub];
        s0 += ((const f32x4*)(edge_attr + (size_t)ea * D))[q];
        s1 += ((const f32x4*)(edge_attr + (size_t)eb * D))[q];
        s2 += ((const f32x4*)(edge_attr + (size_t)ec * D))[q];
        s3 += ((const f32x4*)(edge_attr + (size_t)ed * D))[q];
    }
    for (; k + 4 <= c; k += 4) {
        int ea = bk[k + sub];
        s0 += ((const f32x4*)(edge_attr + (size_t)ea * D))[q];
    }
    int rem = c - k;              // 0..3 leftover edges
    if (sub < rem) {
        int ea = bk[k + sub];
        s1 += ((const f32x4*)(edge_attr + (size_t)ea * D))[q];
    }
    f32x4 s = (s0 + s1) + (s2 + s3);

    // reduce across the 4 sub-groups: lanes l, l^16, l^32, l^48
    s.x += __shfl_xor(s.x, 16, 64); s.y += __shfl_xor(s.y, 16, 64);
    s.z += __shfl_xor(s.z, 16, 64); s.w += __shfl_xor(s.w, 16, 64);
    s.x += __shfl_xor(s.x, 32, 64); s.y += __shfl_xor(s.y, 32, 64);
    s.z += __shfl_xor(s.z, 32, 64); s.w += __shfl_xor(s.w, 32, 64);

    float scale = 0.5f / (float)((c > 0) ? c : 1);
    f32x4 na = ((const f32x4*)(node_attr + (size_t)n * D))[q];
    f32x4 ms = na + s * scale;    // every lane holds features 4q..4q+3 (replicated over sub)

    // publish ms row to per-wave LDS buffer (sub==0 lanes: 16 lanes x 16 B,
    // banks 4q+p -> each bank hit twice = free)
    if (sub == 0) msbuf[wv][q] = ms;
    asm volatile("s_waitcnt lgkmcnt(0)" ::: "memory");
    __builtin_amdgcn_sched_barrier(0);

    float acc = bias[lane];
    const f32x4* __restrict__ mrow = msbuf[wv];
    #pragma unroll
    for (int ii = 0; ii < 16; ++ii) {
        f32x4 mm = mrow[ii];                       // wave-uniform broadcast read
        acc = fmaf(mm.x, Wt[(4 * ii + 0) * (D + 1) + lane], acc);
        acc = fmaf(mm.y, Wt[(4 * ii + 1) * (D + 1) + lane], acc);
        acc = fmaf(mm.z, Wt[(4 * ii + 2) * (D + 1) + lane], acc);
        acc = fmaf(mm.w, Wt[(4 * ii + 3) * (D + 1) + lane], acc);
    }
    node_emb[(size_t)n * D + lane] = 1.0f / (1.0f + __expf(-acc));
}

// ---------------------------------------------------------------------------
// Phase 5: out[e] = 0.5*(node_emb[src[e]] + node_emb[dst[e]])
// 32 B per thread (2 x f32x4). Output written once, never re-read ->
// non-temporal stores (stores only; gathers stay cached for L2/L3 reuse).
// ---------------------------------------------------------------------------
__global__ __launch_bounds__(256) void edge_kernel(
    const int* __restrict__ edge_index,
    const f32x4* __restrict__ node_emb,   // [N_NODES*16] vec4
    f32x4* __restrict__ out)              // [N_EDGES*16] vec4
{
    int t = blockIdx.x * blockDim.x + threadIdx.x;   // < E*8 = 6.4M
    if (t >= N_EDGES * 8) return;
    int e = t >> 3;
    int q = t & 7;                 // 32-B chunk
    int src = edge_index[e];
    int dst = edge_index[N_EDGES + e];
    f32x4 a0 = node_emb[src * 16 + 2 * q];
    f32x4 a1 = node_emb[src * 16 + 2 * q + 1];
    f32x4 c0 = node_emb[dst * 16 + 2 * q];
    f32x4 c1 = node_emb[dst * 16 + 2 * q + 1];
    __builtin_nontemporal_store((a0 + c0) * 0.5f, out + 2 * t);
    __builtin_nontemporal_store((a1 + c1) * 0.5f, out + 2 * t + 1);
}

extern "C" void kernel_launch(void* const* d_in, const int* in_sizes, int n_in,
                              void* d_out, int out_size, void* d_ws, size_t ws_size,
                              hipStream_t stream) {
    const float* edge_attr  = (const float*)d_in[0];
    const int*   edge_index = (const int*)d_in[1];
    const float* node_attr  = (const float*)d_in[2];
    const float* W          = (const float*)d_in[3];
    const float* bias       = (const float*)d_in[4];
    float* out = (float*)d_out;

    // Workspace layout:
    //   cnt    : int[N_NODES]      @ 0
    //   offs   : int[N_NODES]      @ 200000 B
    //   bsum   : int[256]          @ 400000 B
    //   cursor : int[N_NODES]      @ 401024 B
    //   bucket : int[N_EDGES]      @ 601024 B
    //   node_emb: float[N_NODES*D] @ 3801024 B (16B-aligned)
    char* ws = (char*)d_ws;
    int*   cnt      = (int*)(ws);
    int*   offs     = (int*)(ws + 200000);
    int*   bsum     = (int*)(ws + 400000);
    int*   cursor   = (int*)(ws + 401024);
    int*   bucket   = (int*)(ws + 601024);
    float* node_emb = (float*)(ws + 3801024);

    hipMemsetAsync(cnt, 0, N_NODES * sizeof(int), stream);

    hist_kernel<<<(N_EDGES + 255) / 256, 256, 0, stream>>>(edge_index, cnt);
    scanA_kernel<<<NB_SCAN, 256, 0, stream>>>(cnt, offs, bsum);
    scanB_kernel<<<1, 256, 0, stream>>>(bsum);
    scanC_kernel<<<NB_SCAN, 256, 0, stream>>>(offs, bsum, cursor);
    fill_kernel<<<(N_EDGES + 255) / 256, 256, 0, stream>>>(edge_index, cursor, bucket);
    node_fused_kernel<<<(N_NODES + 3) / 4, 256, 0, stream>>>(
        node_attr, edge_attr, cnt, offs, bucket, W, bias, node_emb);
    edge_kernel<<<(N_EDGES * 8 + 255) / 256, 256, 0, stream>>>(
        edge_index, (const f32x4*)node_emb, (f32x4*)out);
}